// Round 6
// baseline (104.529 us; speedup 1.0000x reference)
//
#include <hip/hip_runtime.h>
#include <stdint.h>

// Shapes fixed by setup_inputs(): x [8192,512] f32, patterns [1024,512] f32,
// edges [7] f32. Outputs: [8192] argmax idx (as f32) ++ [8192] score (cnt/512).
//
// R6: i8 MFMA GEMM over one-hot codes (R5 scheme, proven exact), retiled for
// 4 blocks/CU: block = 128 patterns x 64 rows, wave = 2 pattern-groups x 1
// row-group. Both operands expanded in registers by the IDENTICAL function
// (operand-map symmetry => k-permutation invariance). No LDS, no barriers.
#define NROW 8192
#define NPAT 1024

typedef unsigned long long u64;
typedef unsigned int u32;
typedef unsigned char u8;
typedef __attribute__((ext_vector_type(4))) int i32x4;
typedef __attribute__((ext_vector_type(16))) int i32x16;

__device__ __forceinline__ u32 bin7(float v, float e0, float e1, float e2,
                                    float e3, float e4, float e5, float e6) {
  return (u32)((v > e0) + (v > e1) + (v > e2) + (v > e3) + (v > e4) +
               (v > e5) + (v > e6));
}

// Quantize 16 consecutive dims (4 float4) -> 16 code bytes in an int4.
__device__ __forceinline__ int4 quant16(const float4* s4, float e0, float e1,
                                        float e2, float e3, float e4, float e5,
                                        float e6) {
  int4 out;
  int* od = &out.x;
#pragma unroll
  for (int q = 0; q < 4; ++q) {
    float4 a = s4[q];
    od[q] = (int)(bin7(a.x, e0, e1, e2, e3, e4, e5, e6) |
                  (bin7(a.y, e0, e1, e2, e3, e4, e5, e6) << 8) |
                  (bin7(a.z, e0, e1, e2, e3, e4, e5, e6) << 16) |
                  (bin7(a.w, e0, e1, e2, e3, e4, e5, e6) << 24));
  }
  return out;
}

// ---------------------------------------------------------------------------
// Prep (one dispatch, 1152 blocks):
//  blocks [0,1024):   x -> byte-code cells xcodeT[c][row][16], c = 16-dim
//                     chunk. i = bid*256+tid: row = i&8191, c = i>>13.
//                     Reads: each lane one distinct 64B line; writes coalesced.
//  blocks [1024,1152): patterns -> qpcT[c][pat][16] (reads coalesced, writes
//                     scattered 16B). Also zeroes best_packed.
// ---------------------------------------------------------------------------
__global__ __launch_bounds__(256) void prep_kernel(
    const float* __restrict__ x, const float* __restrict__ patterns,
    const float* __restrict__ edges, u8* __restrict__ xcodeT,
    u8* __restrict__ qpcT, u32* __restrict__ best_packed) {
  const float e0 = edges[0], e1 = edges[1], e2 = edges[2], e3 = edges[3],
              e4 = edges[4], e5 = edges[5], e6 = edges[6];
  const int bid = blockIdx.x, tid = threadIdx.x;

  if (bid < 1024) {
    const int i = bid * 256 + tid;  // 0..262143
    const int row = i & 8191;
    const int c = i >> 13;
    const float4* s4 =
        reinterpret_cast<const float4*>(x + ((size_t)row << 9) + (c << 4));
    int4 out = quant16(s4, e0, e1, e2, e3, e4, e5, e6);
    *reinterpret_cast<int4*>(xcodeT + ((size_t)i << 4)) = out;
  } else {
    const int j = (bid - 1024) * 256 + tid;  // 0..32767
    const int pat = j >> 5;
    const int c = j & 31;
    const float4* s4 = reinterpret_cast<const float4*>(
        patterns + ((size_t)pat << 9) + (c << 4));
    int4 out = quant16(s4, e0, e1, e2, e3, e4, e5, e6);
    *reinterpret_cast<int4*>(qpcT + ((((size_t)c << 10) + pat) << 4)) = out;
    if (j < NROW) best_packed[j] = 0;
  }
}

// Expand 2 dims (code bytes h*2, h*2+1 of dword w) into a 16-byte one-hot
// i8 fragment. Used IDENTICALLY for A (patterns) and B (x rows).
__device__ __forceinline__ i32x4 expand2(u32 w, int h) {
  const u32 q0 = (w >> (h << 4)) & 0xFFu;
  const u32 q1 = (w >> ((h << 4) + 8)) & 0xFFu;
  const u64 v0 = 1ull << (q0 << 3);
  const u64 v1 = 1ull << (q1 << 3);
  i32x4 f;
  f[0] = (int)(u32)v0;
  f[1] = (int)(v0 >> 32);
  f[2] = (int)(u32)v1;
  f[3] = (int)(v1 >> 32);
  return f;
}

// ---------------------------------------------------------------------------
// Match: i8 MFMA GEMM, D[pattern][row]. Block = 256 thr (4 waves), C-tile
// 128 patterns x 64 rows. Wave wid: pattern-pair pp=wid&1 (64 patterns),
// row-group rg=wid>>1 (32 rows) -> 2 accumulators. Grid 1024 blocks = 4
// blocks/CU = 4 waves/SIMD (TLP hides L2 latency + overlaps VALU with MFMA).
// Per 16-dim chunk: 3 coalesced dwordx4 code loads (L2-resident), in-register
// one-hot expansion, 8 MFMAs. No LDS, no barriers, no prefetch regs (VGPR
// kept under the (256,4) 128-cap).
// Epilogue: verified C/D map col=lane&31, row=(reg&3)+8*(reg>>2)+4*(lane>>5);
// packed-key (cnt<<10)|(1023-p) atomicMax preserves first-index argmax.
// ---------------------------------------------------------------------------
__global__ __launch_bounds__(256, 4) void match_kernel(
    const u8* __restrict__ xcodeT,  // [32][8192][16]
    const u8* __restrict__ qpcT,    // [32][1024][16]
    u32* __restrict__ best_packed) {
  const int tid = threadIdx.x;
  const int lane = tid & 63;
  const int h = lane >> 5;
  const int wid = tid >> 6;
  const int rgb = blockIdx.x;  // 0..127 -> 64 rows
  const int pgb = blockIdx.y;  // 0..7   -> 128 patterns

  const int pp = wid & 1;   // pattern-pair within block: groups {2pp, 2pp+1}
  const int rg = wid >> 1;  // row-group within block
  const int row0 = rgb * 64 + rg * 32 + (lane & 31);
  const int m0 = pgb * 128 + pp * 64 + (lane & 31);
  const int m1 = m0 + 32;

  i32x16 acc0 = {0};  // patterns [pbase, pbase+32)
  i32x16 acc1 = {0};  // patterns [pbase+32, pbase+64)

  for (int c = 0; c < 32; ++c) {
    const i32x4 cR = *reinterpret_cast<const i32x4*>(
        xcodeT + (((size_t)(c << 13) + row0) << 4));
    const i32x4 cP0 = *reinterpret_cast<const i32x4*>(
        qpcT + (((size_t)(c << 10) + m0) << 4));
    const i32x4 cP1 = *reinterpret_cast<const i32x4*>(
        qpcT + (((size_t)(c << 10) + m1) << 4));
#pragma unroll
    for (int ks = 0; ks < 4; ++ks) {
      const i32x4 b = expand2((u32)cR[ks], h);
      const i32x4 a0 = expand2((u32)cP0[ks], h);
      const i32x4 a1 = expand2((u32)cP1[ks], h);
      acc0 = __builtin_amdgcn_mfma_i32_32x32x32_i8(a0, b, acc0, 0, 0, 0);
      acc1 = __builtin_amdgcn_mfma_i32_32x32x32_i8(a1, b, acc1, 0, 0, 0);
    }
  }

  const int pbase = pgb * 128 + pp * 64;
  u32 best = 0;
#pragma unroll
  for (int r = 0; r < 16; ++r) {
    const int pl = (r & 3) + 8 * (r >> 2) + 4 * h;
    const u32 k0 = (((u32)acc0[r]) << 10) | (1023u - (u32)(pbase + pl));
    const u32 k1 = (((u32)acc1[r]) << 10) | (1023u - (u32)(pbase + 32 + pl));
    best = k0 > best ? k0 : best;
    best = k1 > best ? k1 : best;
  }
  atomicMax(&best_packed[row0], best);
}

// ---------------------------------------------------------------------------
// Finalize: decode packed -> (index as float, score = cnt/512).
// ---------------------------------------------------------------------------
__global__ __launch_bounds__(256) void finalize_kernel(
    const u32* __restrict__ best_packed, float* __restrict__ out) {
  const int i = blockIdx.x * 256 + threadIdx.x;
  if (i >= NROW) return;
  const u32 v = best_packed[i];
  out[i] = (float)(1023u - (v & 1023u));
  out[NROW + i] = (float)(v >> 10) * (1.0f / 512.0f);
}

extern "C" void kernel_launch(void* const* d_in, const int* in_sizes, int n_in,
                              void* d_out, int out_size, void* d_ws,
                              size_t ws_size, hipStream_t stream) {
  const float* x = (const float*)d_in[0];         // [8192, 512]
  const float* patterns = (const float*)d_in[1];  // [1024, 512]
  const float* edges = (const float*)d_in[2];     // [7]
  float* out = (float*)d_out;                     // 16384 floats

  // Workspace: xcodeT 4MB ++ qpcT 512KB ++ best_packed 32KB = 4.53MB.
  u8* xcodeT = (u8*)d_ws;                      // [32][8192][16]
  u8* qpcT = xcodeT + (size_t)32 * NROW * 16;  // [32][1024][16]
  u32* best_packed = (u32*)(qpcT + (size_t)32 * NPAT * 16);

  prep_kernel<<<1152, 256, 0, stream>>>(x, patterns, edges, xcodeT, qpcT,
                                        best_packed);
  match_kernel<<<dim3(128, 8), 256, 0, stream>>>(xcodeT, qpcT, best_packed);
  finalize_kernel<<<NROW / 256, 256, 0, stream>>>(best_packed, out);
}

// Round 7
// 97.066 us; speedup vs baseline: 1.0769x; 1.0769x over previous
//
#include <hip/hip_runtime.h>
#include <stdint.h>

// Shapes fixed by setup_inputs(): x [8192,512] f32, patterns [1024,512] f32,
// edges [7] f32. Outputs: [8192] argmax idx (as f32) ++ [8192] score (cnt/512).
//
// R7: i8 MFMA GEMM over one-hot codes. R5's proven wave tile (2 pattern-groups
// x 2 row-groups, register prefetch, symmetric in-register expand) + K-split
// across wave pairs (8-wave block, LDS merge) for 4 waves/SIMD, + pre-shifted
// codes (bin<<3) to cut expand to 4 VALU instrs.
#define NROW 8192
#define NPAT 1024

typedef unsigned long long u64;
typedef unsigned int u32;
typedef unsigned char u8;
typedef __attribute__((ext_vector_type(4))) int i32x4;
typedef __attribute__((ext_vector_type(16))) int i32x16;

__device__ __forceinline__ u32 bin7(float v, float e0, float e1, float e2,
                                    float e3, float e4, float e5, float e6) {
  return (u32)((v > e0) + (v > e1) + (v > e2) + (v > e3) + (v > e4) +
               (v > e5) + (v > e6));
}

// Quantize 16 consecutive dims -> 16 code bytes, PRE-SHIFTED (bin<<3).
__device__ __forceinline__ int4 quant16s(const float4* s4, float e0, float e1,
                                         float e2, float e3, float e4,
                                         float e5, float e6) {
  int4 out;
  int* od = &out.x;
#pragma unroll
  for (int q = 0; q < 4; ++q) {
    float4 a = s4[q];
    od[q] = (int)((bin7(a.x, e0, e1, e2, e3, e4, e5, e6) << 3) |
                  ((bin7(a.y, e0, e1, e2, e3, e4, e5, e6) << 3) << 8) |
                  ((bin7(a.z, e0, e1, e2, e3, e4, e5, e6) << 3) << 16) |
                  ((bin7(a.w, e0, e1, e2, e3, e4, e5, e6) << 3) << 24));
  }
  return out;
}

// ---------------------------------------------------------------------------
// Prep (one dispatch, 1152 blocks):
//  blocks [0,1024):   x -> shifted byte-code cells xcodeT[c][row][16].
//  blocks [1024,1152): patterns -> qpcT[c][pat][16]; zero best_packed.
// ---------------------------------------------------------------------------
__global__ __launch_bounds__(256) void prep_kernel(
    const float* __restrict__ x, const float* __restrict__ patterns,
    const float* __restrict__ edges, u8* __restrict__ xcodeT,
    u8* __restrict__ qpcT, u32* __restrict__ best_packed) {
  const float e0 = edges[0], e1 = edges[1], e2 = edges[2], e3 = edges[3],
              e4 = edges[4], e5 = edges[5], e6 = edges[6];
  const int bid = blockIdx.x, tid = threadIdx.x;

  if (bid < 1024) {
    const int i = bid * 256 + tid;  // 0..262143
    const int row = i & 8191;
    const int c = i >> 13;
    const float4* s4 =
        reinterpret_cast<const float4*>(x + ((size_t)row << 9) + (c << 4));
    int4 out = quant16s(s4, e0, e1, e2, e3, e4, e5, e6);
    *reinterpret_cast<int4*>(xcodeT + ((size_t)i << 4)) = out;
  } else {
    const int j = (bid - 1024) * 256 + tid;  // 0..32767
    const int pat = j >> 5;
    const int c = j & 31;
    const float4* s4 = reinterpret_cast<const float4*>(
        patterns + ((size_t)pat << 9) + (c << 4));
    int4 out = quant16s(s4, e0, e1, e2, e3, e4, e5, e6);
    *reinterpret_cast<int4*>(qpcT + ((((size_t)c << 10) + pat) << 4)) = out;
    if (j < NROW) best_packed[j] = 0;
  }
}

// Expand 2 dims (pre-shifted code bytes h*2, h*2+1 of dword w) into a 16-byte
// one-hot i8 fragment. 4 VALU instrs. Used IDENTICALLY for A and B
// (operand-map symmetry => k-permutation invariance, proven exact R5/R6).
__device__ __forceinline__ i32x4 expand2s(u32 w, int h) {
  const u32 s0 = (w >> (h << 4)) & 0xFFu;         // already bin*8
  const u32 s1 = (w >> ((h << 4) + 8)) & 0xFFu;
  const u64 v0 = 1ull << s0;
  const u64 v1 = 1ull << s1;
  i32x4 f;
  f[0] = (int)(u32)v0;
  f[1] = (int)(v0 >> 32);
  f[2] = (int)(u32)v1;
  f[3] = (int)(v1 >> 32);
  return f;
}

// ---------------------------------------------------------------------------
// Match: i8 MFMA GEMM, D[pattern][row]. Block = 512 thr (8 waves), C-tile
// 128 patterns x 128 rows. Wave-slot ws = wid&3: pp = ws&1 (64-pattern pair),
// rr = ws>>1 (64-row pair) -> R5's 4-acc tile. K-split kw = wid>>2: waves 0-3
// run chunks 0..15, waves 4-7 run chunks 16..31; partial counts merged via
// 16KB LDS (4 rounds), then low waves run the verified epilogue.
// Grid dim3(8 pgb, 64 rgb) -> consecutive blocks share the same 128 rows
// (xcodeT slice stays hot in L2). 512 blocks = 2 blocks/CU = 4 waves/SIMD.
// ---------------------------------------------------------------------------
__global__ __launch_bounds__(512, 4) void match_kernel(
    const u8* __restrict__ xcodeT,  // [32][8192][16]
    const u8* __restrict__ qpcT,    // [32][1024][16]
    u32* __restrict__ best_packed) {
  __shared__ int lds_m[4][64][16];  // 16 KB merge buffer

  const int tid = threadIdx.x;
  const int lane = tid & 63;
  const int h = lane >> 5;
  const int wid = tid >> 6;
  const int ws = wid & 3;   // wave-slot -> tile position
  const int kw = wid >> 2;  // k-half
  const int pgb = blockIdx.x;  // 0..7  -> 128 patterns
  const int rgb = blockIdx.y;  // 0..63 -> 128 rows

  const int pp = ws & 1;
  const int rr = ws >> 1;
  const int row0 = rgb * 128 + rr * 64 + (lane & 31);
  const int m0 = pgb * 128 + pp * 64 + (lane & 31);

  // Base pointers for this wave's k-half; row1/m1 handled via +512B offsets.
  const int cbeg = kw * 16;
  const u8* pR = xcodeT + ((((size_t)cbeg << 13) + row0) << 4);
  const u8* pP = qpcT + ((((size_t)cbeg << 10) + m0) << 4);

  i32x16 acc00 = {0};  // (pat group m0..+31,  row0)
  i32x16 acc10 = {0};  // (pat group m0+32..,  row0)
  i32x16 acc01 = {0};  // (pat group m0..+31,  row1)
  i32x16 acc11 = {0};  // (pat group m0+32..,  row1)

  i32x4 cR0 = *reinterpret_cast<const i32x4*>(pR);
  i32x4 cR1 = *reinterpret_cast<const i32x4*>(pR + 512);
  i32x4 cP0 = *reinterpret_cast<const i32x4*>(pP);
  i32x4 cP1 = *reinterpret_cast<const i32x4*>(pP + 512);

  for (int c = 0; c < 16; ++c) {
    i32x4 nR0, nR1, nP0, nP1;
    if (c < 15) {
      const size_t ro = (size_t)(c + 1) << 17;  // 8192*16 B per chunk
      const size_t po = (size_t)(c + 1) << 14;  // 1024*16 B per chunk
      nR0 = *reinterpret_cast<const i32x4*>(pR + ro);
      nR1 = *reinterpret_cast<const i32x4*>(pR + ro + 512);
      nP0 = *reinterpret_cast<const i32x4*>(pP + po);
      nP1 = *reinterpret_cast<const i32x4*>(pP + po + 512);
    }
#pragma unroll
    for (int ks = 0; ks < 4; ++ks) {
      const i32x4 a0 = expand2s((u32)cP0[ks], h);
      const i32x4 a1 = expand2s((u32)cP1[ks], h);
      const i32x4 b0 = expand2s((u32)cR0[ks], h);
      const i32x4 b1 = expand2s((u32)cR1[ks], h);
      acc00 = __builtin_amdgcn_mfma_i32_32x32x32_i8(a0, b0, acc00, 0, 0, 0);
      acc10 = __builtin_amdgcn_mfma_i32_32x32x32_i8(a1, b0, acc10, 0, 0, 0);
      acc01 = __builtin_amdgcn_mfma_i32_32x32x32_i8(a0, b1, acc01, 0, 0, 0);
      acc11 = __builtin_amdgcn_mfma_i32_32x32x32_i8(a1, b1, acc11, 0, 0, 0);
    }
    if (c < 15) {
      cR0 = nR0;
      cR1 = nR1;
      cP0 = nP0;
      cP1 = nP1;
    }
  }

  // Merge k-halves: 4 rounds (one per accumulator), high waves write,
  // low waves add. All threads hit both barriers each round.
#pragma unroll
  for (int r = 0; r < 4; ++r) {
    const i32x16* src = (r == 0) ? &acc00 : (r == 1) ? &acc10
                                 : (r == 2) ? &acc01 : &acc11;
    i32x16* dst = (r == 0) ? &acc00 : (r == 1) ? &acc10
                          : (r == 2) ? &acc01 : &acc11;
    if (kw == 1) {
#pragma unroll
      for (int j = 0; j < 16; ++j) lds_m[ws][lane][j] = (*src)[j];
    }
    __syncthreads();
    if (kw == 0) {
#pragma unroll
      for (int j = 0; j < 16; ++j) (*dst)[j] += lds_m[ws][lane][j];
    }
    __syncthreads();
  }

  if (kw == 0) {
    // Epilogue (verified C/D map col=lane&31, row=(reg&3)+8*(reg>>2)+4*h).
    const int pbase = pgb * 128 + pp * 64;
    u32 best0 = 0, best1 = 0;
#pragma unroll
    for (int r = 0; r < 16; ++r) {
      const int pl = (r & 3) + 8 * (r >> 2) + 4 * h;
      const u32 key0 = 1023u - (u32)(pbase + pl);
      const u32 key1 = 1023u - (u32)(pbase + 32 + pl);
      const u32 k00 = (((u32)acc00[r]) << 10) | key0;
      const u32 k10 = (((u32)acc10[r]) << 10) | key1;
      const u32 k01 = (((u32)acc01[r]) << 10) | key0;
      const u32 k11 = (((u32)acc11[r]) << 10) | key1;
      best0 = k00 > best0 ? k00 : best0;
      best0 = k10 > best0 ? k10 : best0;
      best1 = k01 > best1 ? k01 : best1;
      best1 = k11 > best1 ? k11 : best1;
    }
    atomicMax(&best_packed[row0], best0);
    atomicMax(&best_packed[row0 + 32], best1);
  }
}

// ---------------------------------------------------------------------------
// Finalize: decode packed -> (index as float, score = cnt/512).
// ---------------------------------------------------------------------------
__global__ __launch_bounds__(256) void finalize_kernel(
    const u32* __restrict__ best_packed, float* __restrict__ out) {
  const int i = blockIdx.x * 256 + threadIdx.x;
  if (i >= NROW) return;
  const u32 v = best_packed[i];
  out[i] = (float)(1023u - (v & 1023u));
  out[NROW + i] = (float)(v >> 10) * (1.0f / 512.0f);
}

extern "C" void kernel_launch(void* const* d_in, const int* in_sizes, int n_in,
                              void* d_out, int out_size, void* d_ws,
                              size_t ws_size, hipStream_t stream) {
  const float* x = (const float*)d_in[0];         // [8192, 512]
  const float* patterns = (const float*)d_in[1];  // [1024, 512]
  const float* edges = (const float*)d_in[2];     // [7]
  float* out = (float*)d_out;                     // 16384 floats

  // Workspace: xcodeT 4MB ++ qpcT 512KB ++ best_packed 32KB = 4.53MB.
  u8* xcodeT = (u8*)d_ws;                      // [32][8192][16]
  u8* qpcT = xcodeT + (size_t)32 * NROW * 16;  // [32][1024][16]
  u32* best_packed = (u32*)(qpcT + (size_t)32 * NPAT * 16);

  prep_kernel<<<1152, 256, 0, stream>>>(x, patterns, edges, xcodeT, qpcT,
                                        best_packed);
  match_kernel<<<dim3(8, 64), 512, 0, stream>>>(xcodeT, qpcT, best_packed);
  finalize_kernel<<<NROW / 256, 256, 0, stream>>>(best_packed, out);
}

// Round 8
// 92.591 us; speedup vs baseline: 1.1289x; 1.0483x over previous
//
#include <hip/hip_runtime.h>
#include <stdint.h>

// Shapes fixed by setup_inputs(): x [8192,512] f32, patterns [1024,512] f32,
// edges [7] f32. Outputs: [8192] argmax idx (as f32) ++ [8192] score (cnt/512).
//
// R8: 2 dispatches only. prep quantizes to pre-shifted byte-codes; match is an
// i8 MFMA GEMM where each block owns 32 rows x ALL 1024 patterns, so the
// argmax finishes in-block (LDS+shuffle) and writes out[] directly -- no
// best_packed, no atomics, no finalize dispatch. Operand fragments for A and
// B are expanded in-register by the IDENTICAL function (symmetry => k-perm
// invariance, proven exact R5-R7).
#define NROW 8192
#define NPAT 1024

typedef unsigned long long u64;
typedef unsigned int u32;
typedef unsigned char u8;
typedef __attribute__((ext_vector_type(4))) int i32x4;
typedef __attribute__((ext_vector_type(16))) int i32x16;

__device__ __forceinline__ u32 bin7(float v, float e0, float e1, float e2,
                                    float e3, float e4, float e5, float e6) {
  return (u32)((v > e0) + (v > e1) + (v > e2) + (v > e3) + (v > e4) +
               (v > e5) + (v > e6));
}

// Quantize 16 consecutive dims -> 16 code bytes, PRE-SHIFTED (bin<<3).
__device__ __forceinline__ int4 quant16s(const float4* s4, float e0, float e1,
                                         float e2, float e3, float e4,
                                         float e5, float e6) {
  int4 out;
  int* od = &out.x;
#pragma unroll
  for (int q = 0; q < 4; ++q) {
    float4 a = s4[q];
    od[q] = (int)((bin7(a.x, e0, e1, e2, e3, e4, e5, e6) << 3) |
                  ((bin7(a.y, e0, e1, e2, e3, e4, e5, e6) << 3) << 8) |
                  ((bin7(a.z, e0, e1, e2, e3, e4, e5, e6) << 3) << 16) |
                  ((bin7(a.w, e0, e1, e2, e3, e4, e5, e6) << 3) << 24));
  }
  return out;
}

// ---------------------------------------------------------------------------
// Prep (one dispatch, 1152 blocks):
//  blocks [0,1024):   x -> shifted byte-code cells xcodeT[c][row][16].
//  blocks [1024,1152): patterns -> qpcT[c][pat][16].
// ---------------------------------------------------------------------------
__global__ __launch_bounds__(256) void prep_kernel(
    const float* __restrict__ x, const float* __restrict__ patterns,
    const float* __restrict__ edges, u8* __restrict__ xcodeT,
    u8* __restrict__ qpcT) {
  const float e0 = edges[0], e1 = edges[1], e2 = edges[2], e3 = edges[3],
              e4 = edges[4], e5 = edges[5], e6 = edges[6];
  const int bid = blockIdx.x, tid = threadIdx.x;

  if (bid < 1024) {
    const int i = bid * 256 + tid;  // 0..262143
    const int row = i & 8191;
    const int c = i >> 13;
    const float4* s4 =
        reinterpret_cast<const float4*>(x + ((size_t)row << 9) + (c << 4));
    int4 out = quant16s(s4, e0, e1, e2, e3, e4, e5, e6);
    *reinterpret_cast<int4*>(xcodeT + ((size_t)i << 4)) = out;
  } else {
    const int j = (bid - 1024) * 256 + tid;  // 0..32767
    const int pat = j >> 5;
    const int c = j & 31;
    const float4* s4 = reinterpret_cast<const float4*>(
        patterns + ((size_t)pat << 9) + (c << 4));
    int4 out = quant16s(s4, e0, e1, e2, e3, e4, e5, e6);
    *reinterpret_cast<int4*>(qpcT + ((((size_t)c << 10) + pat) << 4)) = out;
  }
}

// Expand 2 dims (pre-shifted code bytes h*2, h*2+1 of dword w) into a 16-byte
// one-hot i8 fragment. Used IDENTICALLY for A and B.
__device__ __forceinline__ i32x4 expand2s(u32 w, int hs) {
  const u32 s0 = (w >> hs) & 0xFFu;        // already bin*8
  const u32 s1 = (w >> (hs + 8)) & 0xFFu;
  const u64 v0 = 1ull << s0;
  const u64 v1 = 1ull << s1;
  i32x4 f;
  f[0] = (int)(u32)v0;
  f[1] = (int)(v0 >> 32);
  f[2] = (int)(u32)v1;
  f[3] = (int)(v1 >> 32);
  return f;
}

// ---------------------------------------------------------------------------
// Match+argmax+finalize in ONE kernel. Grid 256 blocks x 512 thr (8 waves,
// 1 block/CU, 2 waves/SIMD). Block b owns rows b*32..+31 and ALL 1024
// patterns: wave w -> patterns w*128 + q*32 + (lane&31), q=0..3 (4 accs,
// MFMA dependency distance 4 -- R5-proven). B fragment (x row) shared by all
// 4 accs -> 20 expands per 16 MFMAs. Software prefetch of next chunk.
// Epilogue: fold accs into packed keys (cnt<<10)|(1023-m), LDS-reduce over
// 8 waves + shuffle-reduce over lane-halves, wave 0 writes out[] directly.
// ---------------------------------------------------------------------------
__global__ __launch_bounds__(512, 2) void match_kernel(
    const u8* __restrict__ xcodeT,  // [32][8192][16]
    const u8* __restrict__ qpcT,    // [32][1024][16]
    float* __restrict__ out) {
  __shared__ u32 lds_best[8][64];  // 2 KB

  const int tid = threadIdx.x;
  const int lane = tid & 63;
  const int hs = (lane >> 5) << 4;  // 0 or 16: bit offset of this k-half
  const int wid = tid >> 6;         // 0..7
  const int row = blockIdx.x * 32 + (lane & 31);
  const int m0 = wid * 128 + (lane & 31);  // patterns m0 + q*32

  const u8* pR = xcodeT + ((size_t)row << 4);
  const u8* pP = qpcT + ((size_t)m0 << 4);

  i32x16 acc0 = {0}, acc1 = {0}, acc2 = {0}, acc3 = {0};

  i32x4 cR = *reinterpret_cast<const i32x4*>(pR);
  i32x4 cP0 = *reinterpret_cast<const i32x4*>(pP);
  i32x4 cP1 = *reinterpret_cast<const i32x4*>(pP + 512);
  i32x4 cP2 = *reinterpret_cast<const i32x4*>(pP + 1024);
  i32x4 cP3 = *reinterpret_cast<const i32x4*>(pP + 1536);

  for (int c = 0; c < 32; ++c) {
    i32x4 nR, nP0, nP1, nP2, nP3;
    if (c < 31) {
      const size_t ro = (size_t)(c + 1) << 17;  // 8192*16 B per chunk
      const size_t po = (size_t)(c + 1) << 14;  // 1024*16 B per chunk
      nR = *reinterpret_cast<const i32x4*>(pR + ro);
      nP0 = *reinterpret_cast<const i32x4*>(pP + po);
      nP1 = *reinterpret_cast<const i32x4*>(pP + po + 512);
      nP2 = *reinterpret_cast<const i32x4*>(pP + po + 1024);
      nP3 = *reinterpret_cast<const i32x4*>(pP + po + 1536);
    }
#pragma unroll
    for (int ks = 0; ks < 4; ++ks) {
      const i32x4 b = expand2s((u32)cR[ks], hs);
      const i32x4 a0 = expand2s((u32)cP0[ks], hs);
      const i32x4 a1 = expand2s((u32)cP1[ks], hs);
      const i32x4 a2 = expand2s((u32)cP2[ks], hs);
      const i32x4 a3 = expand2s((u32)cP3[ks], hs);
      acc0 = __builtin_amdgcn_mfma_i32_32x32x32_i8(a0, b, acc0, 0, 0, 0);
      acc1 = __builtin_amdgcn_mfma_i32_32x32x32_i8(a1, b, acc1, 0, 0, 0);
      acc2 = __builtin_amdgcn_mfma_i32_32x32x32_i8(a2, b, acc2, 0, 0, 0);
      acc3 = __builtin_amdgcn_mfma_i32_32x32x32_i8(a3, b, acc3, 0, 0, 0);
    }
    if (c < 31) {
      cR = nR;
      cP0 = nP0;
      cP1 = nP1;
      cP2 = nP2;
      cP3 = nP3;
    }
  }

  // Fold accumulators into one packed best key per (wave, lane).
  // C/D map (HW-verified): col = lane&31 (this lane's row), row-in-tile
  // pl = (r&3) + 8*(r>>2) + 4*(lane>>5). Pattern index = wid*128 + q*32 + pl.
  const int hq = hs >> 2;  // 4*h
  u32 best = 0;
#pragma unroll
  for (int r = 0; r < 16; ++r) {
    const int pl = (r & 3) + 8 * (r >> 2) + hq;
    const u32 k0 = (((u32)acc0[r]) << 10) | (1023u - (u32)(m0 - (lane & 31) + pl));
    const u32 k1 = (((u32)acc1[r]) << 10) | (1023u - (u32)(m0 - (lane & 31) + 32 + pl));
    const u32 k2 = (((u32)acc2[r]) << 10) | (1023u - (u32)(m0 - (lane & 31) + 64 + pl));
    const u32 k3 = (((u32)acc3[r]) << 10) | (1023u - (u32)(m0 - (lane & 31) + 96 + pl));
    best = k0 > best ? k0 : best;
    best = k1 > best ? k1 : best;
    best = k2 > best ? k2 : best;
    best = k3 > best ? k3 : best;
  }
  lds_best[wid][lane] = best;
  __syncthreads();

  if (wid == 0) {
    u32 t = lds_best[0][lane];
#pragma unroll
    for (int w = 1; w < 8; ++w) {
      const u32 v = lds_best[w][lane];
      t = v > t ? v : t;
    }
    const u32 o = __shfl_down(t, 32);  // lane < 32 gets lane+32's key
    if (lane < 32) {
      const u32 f = o > t ? o : t;
      out[row] = (float)(1023u - (f & 1023u));
      out[NROW + row] = (float)(f >> 10) * (1.0f / 512.0f);
    }
  }
}

extern "C" void kernel_launch(void* const* d_in, const int* in_sizes, int n_in,
                              void* d_out, int out_size, void* d_ws,
                              size_t ws_size, hipStream_t stream) {
  const float* x = (const float*)d_in[0];         // [8192, 512]
  const float* patterns = (const float*)d_in[1];  // [1024, 512]
  const float* edges = (const float*)d_in[2];     // [7]
  float* out = (float*)d_out;                     // 16384 floats

  // Workspace: xcodeT 4MB ++ qpcT 512KB.
  u8* xcodeT = (u8*)d_ws;                      // [32][8192][16]
  u8* qpcT = xcodeT + (size_t)32 * NROW * 16;  // [32][1024][16]

  prep_kernel<<<1152, 256, 0, stream>>>(x, patterns, edges, xcodeT, qpcT);
  match_kernel<<<256, 512, 0, stream>>>(xcodeT, qpcT, out);
}

// Round 9
// 85.734 us; speedup vs baseline: 1.2192x; 1.0800x over previous
//
#include <hip/hip_runtime.h>
#include <stdint.h>

// Shapes fixed by setup_inputs(): x [8192,512] f32, patterns [1024,512] f32,
// edges [7] f32. Outputs: [8192] argmax idx (as f32) ++ [8192] score (cnt/512).
//
// R9: MX-fp4 MFMA GEMM (mfma_scale_f32_32x32x64_f8f6f4, FMT=4, scales=1.0).
// One-hot codes as fp4 nibbles (1.0 = 0x2 at nibble 'bin'): K=64/instr halves
// the matrix-pipe work vs i8 (the R5-R8 invariant bottleneck). A and B
// fragments built by the IDENTICAL expansion (symmetry => k-permutation
// invariance, proven exact R5-R8). fp32 accumulation of <=512 ones is exact.
// Fused block-level argmax (R8 structure): 2 dispatches total.
#define NROW 8192
#define NPAT 1024

typedef unsigned long long u64;
typedef unsigned int u32;
typedef unsigned char u8;
typedef __attribute__((ext_vector_type(4))) int i32x4;
typedef __attribute__((ext_vector_type(8))) int i32x8;
typedef __attribute__((ext_vector_type(16))) float f32x16;

__device__ __forceinline__ u32 bin7(float v, float e0, float e1, float e2,
                                    float e3, float e4, float e5, float e6) {
  return (u32)((v > e0) + (v > e1) + (v > e2) + (v > e3) + (v > e4) +
               (v > e5) + (v > e6));
}

// Quantize 16 consecutive dims -> 16 code bytes, PRE-SHIFTED (bin*4).
__device__ __forceinline__ int4 quant16n(const float4* s4, float e0, float e1,
                                         float e2, float e3, float e4,
                                         float e5, float e6) {
  int4 out;
  int* od = &out.x;
#pragma unroll
  for (int q = 0; q < 4; ++q) {
    float4 a = s4[q];
    od[q] = (int)((bin7(a.x, e0, e1, e2, e3, e4, e5, e6) << 2) |
                  ((bin7(a.y, e0, e1, e2, e3, e4, e5, e6) << 2) << 8) |
                  ((bin7(a.z, e0, e1, e2, e3, e4, e5, e6) << 2) << 16) |
                  ((bin7(a.w, e0, e1, e2, e3, e4, e5, e6) << 2) << 24));
  }
  return out;
}

// ---------------------------------------------------------------------------
// Prep: codes layout [c16 0..31][h 0..1][row][8B]: h*8 dims per 8-byte cell,
// so a lane's k-half (h = lane>>5) for one 16-dim iteration is ONE dwordx2.
//  blocks [0,1024):   x -> xcode2 (4 MB). Writes coalesced (consecutive rows).
//  blocks [1024,1152): patterns -> qpc2 (512 KB).
// ---------------------------------------------------------------------------
__global__ __launch_bounds__(256) void prep_kernel(
    const float* __restrict__ x, const float* __restrict__ patterns,
    const float* __restrict__ edges, u8* __restrict__ xcode2,
    u8* __restrict__ qpc2) {
  const float e0 = edges[0], e1 = edges[1], e2 = edges[2], e3 = edges[3],
              e4 = edges[4], e5 = edges[5], e6 = edges[6];
  const int bid = blockIdx.x, tid = threadIdx.x;

  if (bid < 1024) {
    const int i = bid * 256 + tid;  // 0..262143
    const int row = i & 8191;
    const int c16 = i >> 13;
    const float4* s4 =
        reinterpret_cast<const float4*>(x + ((size_t)row << 9) + (c16 << 4));
    int4 cod = quant16n(s4, e0, e1, e2, e3, e4, e5, e6);
    const u64 lo = (u64)(u32)cod.x | ((u64)(u32)cod.y << 32);  // dims 0..7
    const u64 hi = (u64)(u32)cod.z | ((u64)(u32)cod.w << 32);  // dims 8..15
    *reinterpret_cast<u64*>(
        xcode2 + ((((size_t)c16 * 2 + 0) * 8192 + row) << 3)) = lo;
    *reinterpret_cast<u64*>(
        xcode2 + ((((size_t)c16 * 2 + 1) * 8192 + row) << 3)) = hi;
  } else {
    const int j = (bid - 1024) * 256 + tid;  // 0..32767
    const int pat = j >> 5;
    const int c16 = j & 31;
    const float4* s4 = reinterpret_cast<const float4*>(
        patterns + ((size_t)pat << 9) + (c16 << 4));
    int4 cod = quant16n(s4, e0, e1, e2, e3, e4, e5, e6);
    const u64 lo = (u64)(u32)cod.x | ((u64)(u32)cod.y << 32);
    const u64 hi = (u64)(u32)cod.z | ((u64)(u32)cod.w << 32);
    *reinterpret_cast<u64*>(
        qpc2 + ((((size_t)c16 * 2 + 0) * 1024 + pat) << 3)) = lo;
    *reinterpret_cast<u64*>(
        qpc2 + ((((size_t)c16 * 2 + 1) * 1024 + pat) << 3)) = hi;
  }
}

// Expand 4 dims (pre-shifted codes bin*4 in the 4 bytes of w) into 4 dwords
// of fp4 one-hot nibbles: dword t = 1.0fp4 (0x2) at nibble bin. Used
// IDENTICALLY for A and B.
__device__ __forceinline__ i32x4 expand4(u32 w) {
  i32x4 f;
  f[0] = (int)(2u << (w & 0xFFu));
  f[1] = (int)(2u << ((w >> 8) & 0xFFu));
  f[2] = (int)(2u << ((w >> 16) & 0xFFu));
  f[3] = (int)(2u << (w >> 24));
  return f;
}

__device__ __forceinline__ i32x8 make8(i32x4 v) {
  i32x8 r;
  r[0] = v[0]; r[1] = v[1]; r[2] = v[2]; r[3] = v[3];
  r[4] = 0; r[5] = 0; r[6] = 0; r[7] = 0;  // fp4 uses regs 0-3; zero the rest
  return r;
}

#define MFMA_FP4(A, B, C)                                                \
  __builtin_amdgcn_mfma_scale_f32_32x32x64_f8f6f4(                       \
      (A), (B), (C), 4, 4, 0, 0x7F7F7F7F, 0, 0x7F7F7F7F)

// ---------------------------------------------------------------------------
// Match+argmax in ONE kernel. Grid 256 blocks x 512 thr (8 waves, 1 block/CU).
// Block b: rows b*32..+31, ALL 1024 patterns. Wave w: patterns w*128+q*32,
// q=0..3 (4 fp32 accs). Iteration = 16 dims = 2 MFMAs per acc (j=0,1; k-slot
// j covers dims c16*16 + h*8 + j*4 + t, identical for A and B). B fragment
// shared by 4 accs. Software prefetch of next iteration's 5 u64 code cells.
// Epilogue: cvt fp32 counts (exact ints) -> packed keys -> LDS+shuffle argmax,
// wave 0 writes out[] directly.
// ---------------------------------------------------------------------------
__global__ __launch_bounds__(512, 2) void match_kernel(
    const u8* __restrict__ xcode2,  // [32][2][8192][8]
    const u8* __restrict__ qpc2,    // [32][2][1024][8]
    float* __restrict__ out) {
  __shared__ u32 lds_best[8][64];  // 2 KB

  const int tid = threadIdx.x;
  const int lane = tid & 63;
  const int h = lane >> 5;
  const int wid = tid >> 6;  // 0..7
  const int row = blockIdx.x * 32 + (lane & 31);
  const int m0 = wid * 128 + (lane & 31);

  const u8* pR = xcode2 + (((size_t)h * 8192 + row) << 3);
  const u8* pP = qpc2 + (((size_t)h * 1024 + m0) << 3);

  f32x16 acc0 = {0}, acc1 = {0}, acc2 = {0}, acc3 = {0};

  u64 cR = *reinterpret_cast<const u64*>(pR);
  u64 cP0 = *reinterpret_cast<const u64*>(pP);
  u64 cP1 = *reinterpret_cast<const u64*>(pP + 256);
  u64 cP2 = *reinterpret_cast<const u64*>(pP + 512);
  u64 cP3 = *reinterpret_cast<const u64*>(pP + 768);

  for (int c = 0; c < 32; ++c) {
    u64 nR, nP0, nP1, nP2, nP3;
    if (c < 31) {
      const size_t ro = (size_t)(c + 1) << 17;  // 2*8192*8 B per iteration
      const size_t po = (size_t)(c + 1) << 14;  // 2*1024*8 B per iteration
      nR = *reinterpret_cast<const u64*>(pR + ro);
      nP0 = *reinterpret_cast<const u64*>(pP + po);
      nP1 = *reinterpret_cast<const u64*>(pP + po + 256);
      nP2 = *reinterpret_cast<const u64*>(pP + po + 512);
      nP3 = *reinterpret_cast<const u64*>(pP + po + 768);
    }
#pragma unroll
    for (int j = 0; j < 2; ++j) {
      const i32x8 b8 = make8(expand4((u32)(cR >> (32 * j))));
      const i32x8 a0 = make8(expand4((u32)(cP0 >> (32 * j))));
      const i32x8 a1 = make8(expand4((u32)(cP1 >> (32 * j))));
      const i32x8 a2 = make8(expand4((u32)(cP2 >> (32 * j))));
      const i32x8 a3 = make8(expand4((u32)(cP3 >> (32 * j))));
      acc0 = MFMA_FP4(a0, b8, acc0);
      acc1 = MFMA_FP4(a1, b8, acc1);
      acc2 = MFMA_FP4(a2, b8, acc2);
      acc3 = MFMA_FP4(a3, b8, acc3);
    }
    if (c < 31) {
      cR = nR;
      cP0 = nP0;
      cP1 = nP1;
      cP2 = nP2;
      cP3 = nP3;
    }
  }

  // Fold accs -> one packed key. C/D map (shape-determined, HW-verified):
  // col = lane&31 (this lane's row), pl = (r&3) + 8*(r>>2) + 4*h.
  const int hq = h << 2;
  const int wbase = wid * 128;
  u32 best = 0;
#pragma unroll
  for (int r = 0; r < 16; ++r) {
    const int pl = (r & 3) + 8 * (r >> 2) + hq;
    const u32 k0 = (((u32)acc0[r]) << 10) | (1023u - (u32)(wbase + pl));
    const u32 k1 = (((u32)acc1[r]) << 10) | (1023u - (u32)(wbase + 32 + pl));
    const u32 k2 = (((u32)acc2[r]) << 10) | (1023u - (u32)(wbase + 64 + pl));
    const u32 k3 = (((u32)acc3[r]) << 10) | (1023u - (u32)(wbase + 96 + pl));
    best = k0 > best ? k0 : best;
    best = k1 > best ? k1 : best;
    best = k2 > best ? k2 : best;
    best = k3 > best ? k3 : best;
  }
  lds_best[wid][lane] = best;
  __syncthreads();

  if (wid == 0) {
    u32 t = lds_best[0][lane];
#pragma unroll
    for (int w = 1; w < 8; ++w) {
      const u32 v = lds_best[w][lane];
      t = v > t ? v : t;
    }
    const u32 o = __shfl_down(t, 32);
    if (lane < 32) {
      const u32 f = o > t ? o : t;
      out[row] = (float)(1023u - (f & 1023u));
      out[NROW + row] = (float)(f >> 10) * (1.0f / 512.0f);
    }
  }
}

extern "C" void kernel_launch(void* const* d_in, const int* in_sizes, int n_in,
                              void* d_out, int out_size, void* d_ws,
                              size_t ws_size, hipStream_t stream) {
  const float* x = (const float*)d_in[0];         // [8192, 512]
  const float* patterns = (const float*)d_in[1];  // [1024, 512]
  const float* edges = (const float*)d_in[2];     // [7]
  float* out = (float*)d_out;                     // 16384 floats

  // Workspace: xcode2 4MB ++ qpc2 512KB.
  u8* xcode2 = (u8*)d_ws;                       // [32][2][8192][8]
  u8* qpc2 = xcode2 + (size_t)64 * NROW * 8;    // [32][2][1024][8]

  prep_kernel<<<1152, 256, 0, stream>>>(x, patterns, edges, xcode2, qpc2);
  match_kernel<<<256, 512, 0, stream>>>(xcode2, qpc2, out);
}